// Round 3
// baseline (213.603 us; speedup 1.0000x reference)
//
#include <hip/hip_runtime.h>

#define T_STEPS 512
#define G_CELLS 4096
#define L_UHN   15
#define NZF     1e-5f
#define LOG2E   1.44269504088896340736f
#define LOG2_10 3.32192809488736234787f

// raw gfx950 transcendental units: v_exp_f32 computes 2^x, v_log_f32 computes log2(x)
__device__ __forceinline__ float fexp2(float x) { return __builtin_amdgcn_exp2f(x); }
__device__ __forceinline__ float flog2(float x) { return __builtin_amdgcn_logf(x); }

__device__ __forceinline__ float fpow(float a, float b) {
    // a must be > 0
    return fexp2(b * flog2(a));
}
__device__ __forceinline__ float fexp(float x) {        // e^x
    return fexp2(x * LOG2E);
}
__device__ __forceinline__ float fsigmoid(float v) {
    return 1.0f / (1.0f + fexp(-v));
}
__device__ __forceinline__ float fdescale(float s, float lo, float hi) {
    return lo + s * (hi - lo);
}

__global__ __launch_bounds__(256) void blend_scan_kernel(
    const float* __restrict__ x,       // (T, G, 3)
    const float* __restrict__ params,  // (T, G, 39)
    float* __restrict__ out)           // (T, G)
{
    const int g = blockIdx.x * blockDim.x + threadIdx.x;
    if (g >= G_CELLS) return;

    // ---- load raw params for this cell (last timestep) ----
    const float* pp = params + ((size_t)(T_STEPS - 1) * G_CELLS + (size_t)g) * 39;
    float raw[39];
    #pragma unroll
    for (int i = 0; i < 39; ++i) raw[i] = pp[i];

    // ---- unpack physical params ----
    const float ddf_min     = fdescale(fsigmoid(raw[0]),  0.0f, 20.0f);
    const float ddf_plus    = fdescale(fsigmoid(raw[1]),  0.0f, 20.0f);
    const float Kcum        = fdescale(fsigmoid(raw[2]),  0.01f, 0.2f);
    const float Kf          = fdescale(fsigmoid(raw[3]),  0.0f, 5.0f);
    const float exp_fe      = fdescale(fsigmoid(raw[4]),  0.0f, 1.0f);
    const float Tbf         = fdescale(fsigmoid(raw[5]), -5.0f, 2.0f);
    const float Ccum        = fdescale(fsigmoid(raw[6]),  0.005f, 0.05f);
    const float SWI         = fdescale(fsigmoid(raw[7]),  0.0f, 0.4f);
    const float Tbm         = fdescale(fsigmoid(raw[8]), -2.0f, 3.0f);
    const float fcmin       = fdescale(fsigmoid(raw[9]),  0.0f, 0.1f);
    const float fcmin_plus  = fdescale(fsigmoid(raw[10]), 0.01f, 0.25f);
    const float vmax        = fdescale(fsigmoid(raw[11]), 0.001f, 500.0f);
    const float hmets_alpha = fdescale(fsigmoid(raw[12]), 0.0f, 1.0f);
    const float vic_beta    = fdescale(fsigmoid(raw[13]), 0.1f, 3.0f);
    const float hbv_beta    = fdescale(fsigmoid(raw[14]), 0.5f, 3.0f);
    const float quickflow_k = fdescale(fsigmoid(raw[15]), -5.0f, -2.0f);
    const float quickflow_n = fdescale(fsigmoid(raw[16]), 0.5f, 2.0f);
    const float mmax        = fdescale(fsigmoid(raw[17]), 0.0f, 100.0f);
    const float lamb        = fdescale(fsigmoid(raw[18]), 5.0f, 10.0f);
    const float baseflow_k  = fdescale(fsigmoid(raw[19]), -5.0f, -1.0f);
    const float baseflow_n  = fdescale(fsigmoid(raw[20]), 0.5f, 2.0f);
    const float ET_eff      = fdescale(fsigmoid(raw[21]), 0.0f, 3.0f);
    const float cv2p        = fdescale(fsigmoid(raw[22]), 1e-5f, 0.02f);
    // raw[23] (coef_phreatic) unused by forward

    // ---- softmax weight groups (on raw values, like reference) ----
    float w1, w2, w3, w4, w5, w6, w7, w8, w9, w10, w11;
    {
        float m = fmaxf(fmaxf(raw[24], raw[25]), raw[26]);
        float e0 = fexp(raw[24] - m), e1 = fexp(raw[25] - m), e2 = fexp(raw[26] - m);
        float inv = 1.0f / (e0 + e1 + e2);
        w1 = e0 * inv; w2 = e1 * inv; w3 = e2 * inv;
    }
    {
        float m = fmaxf(fmaxf(raw[27], raw[28]), raw[29]);
        float e0 = fexp(raw[27] - m), e1 = fexp(raw[28] - m), e2 = fexp(raw[29] - m);
        float inv = 1.0f / (e0 + e1 + e2);
        w4 = e0 * inv; w5 = e1 * inv; w6 = e2 * inv;
    }
    {
        float m = fmaxf(fmaxf(raw[30], raw[31]), raw[32]);
        float e0 = fexp(raw[30] - m), e1 = fexp(raw[31] - m), e2 = fexp(raw[32] - m);
        float inv = 1.0f / (e0 + e1 + e2);
        w7 = e0 * inv; w8 = e1 * inv; w9 = e2 * inv;
    }
    {
        float m = fmaxf(raw[33], raw[34]);
        float e0 = fexp(raw[33] - m), e1 = fexp(raw[34] - m);
        float inv = 1.0f / (e0 + e1);
        w10 = e0 * inv; w11 = e1 * inv;
    }

    // ---- routing params + gamma unit hydrographs ----
    const float a1 = fdescale(fsigmoid(raw[35]), 0.3f, 20.0f);
    const float b1 = fdescale(fsigmoid(raw[36]), 0.01f, 5.0f);
    const float a2 = fdescale(fsigmoid(raw[37]), 0.5f, 13.0f);
    const float b2 = fdescale(fsigmoid(raw[38]), 0.15f, 1.5f);

    const float LOG2T[L_UHN] = {
        -1.0f, 0.58496250072116f, 1.32192809488736f, 1.80735492205760f,
        2.16992500144231f, 2.45943161863730f, 2.70043971814109f,
        2.90689059560852f, 3.08746284125034f, 3.24792751344359f,
        3.39231742277876f, 3.52356195605701f, 3.64385618977472f,
        3.75488750216347f, 3.85798099512757f };

    float uh1[L_UHN], uh2[L_UHN];
    {
        float rb1 = LOG2E / b1, rb2 = LOG2E / b2;
        float s1 = 0.0f, s2 = 0.0f;
        #pragma unroll
        for (int k = 0; k < L_UHN; ++k) {
            float tk = (float)k + 0.5f;
            float v1 = fexp2((a1 - 1.0f) * LOG2T[k] - tk * rb1);
            float v2 = fexp2((a2 - 1.0f) * LOG2T[k] - tk * rb2);
            uh1[k] = v1; uh2[k] = v2; s1 += v1; s2 += v2;
        }
        float i1 = 1.0f / s1, i2 = 1.0f / s2;
        #pragma unroll
        for (int k = 0; k < L_UHN; ++k) { uh1[k] *= i1; uh2[k] *= i2; }
    }

    // ---- per-cell loop constants ----
    const float ddfsum      = ddf_min + ddf_plus;
    const float ddfK        = ddf_min * Kcum;
    const float inv_vmax    = 1.0f / vmax;
    const float qk10        = fexp2(quickflow_k * LOG2_10);
    const float bk10        = fexp2(baseflow_k * LOG2_10);
    const float qf_top_coef = mmax * (vmax / quickflow_n) * fexp2(-quickflow_n * flog2(lamb));
    const float fcsum       = fcmin + fcmin_plus;
    const float c_b1        = w10 * bk10;
    const float c_b2        = w11 * bk10;
    const float w7qk        = w7 * qk10;

    // ---- state ----
    float sp1 = 0.f, lw1 = 0.f, cm1 = 0.f;
    float sp2 = 0.f, lw2 = 0.f, cm2 = 0.f;
    float sp3 = 0.f, cm3 = 0.f;
    float vad = 0.f, phr = 0.f;

    float fut[L_UHN];
    #pragma unroll
    for (int k = 0; k < L_UHN; ++k) fut[k] = 0.0f;

    // ---- main sequential scan ----
    const size_t xstride = (size_t)G_CELLS * 3;
    size_t xi = (size_t)g * 3;
    float cp = x[xi], ct = x[xi + 1], cpe = x[xi + 2];

    for (int t = 0; t < T_STEPS; ++t) {
        // prefetch next step's forcing
        float np_ = 0.f, nt_ = 0.f, npe_ = 0.f;
        if (t + 1 < T_STEPS) {
            size_t ni = xi + xstride;
            np_ = x[ni]; nt_ = x[ni + 1]; npe_ = x[ni + 2];
        }
        xi += xstride;

        const float prcp = cp, tm = ct, pet = cpe;
        const float rain = (tm > 0.0f) ? prcp : 0.0f;
        const float snow = prcp - rain;
        const float frz_pot = fmaxf(Tbf - tm, NZF);

        // --- snobal_hbv ---
        float o1;
        {
            float ddf  = fminf(ddfsum, fmaf(ddfK, cm1, ddf_min));
            float pm   = fmaxf(ddf * (tm - Tbm), 0.0f);
            float rfz  = fminf(Kf * frz_pot, lw1);
            sp1 = sp1 + snow + rfz;
            float melt = fminf(pm, sp1 + snow + rfz);   // reference quirk: sp already updated
            cm1 = (sp1 > NZF) ? (cm1 + melt) : 0.0f;
            sp1 = fmaxf(sp1 - melt, NZF);
            float wret = SWI * sp1;
            float wtmp = lw1 + melt + rain;
            o1 = fmaxf(wtmp - wret, 0.0f);
            lw1 = (o1 > 0.0f) ? wret : wtmp;
        }

        // --- snobal_hmets ---
        float o2;
        {
            float ddf  = fminf(ddfsum, fmaf(ddfK, cm2, ddf_min));
            float pm   = fmaxf(ddf * (tm - Tbm), 0.0f);
            float pfz  = Kf * fpow(frz_pot, exp_fe);
            float rfz  = fminf(pfz, lw2);
            lw2 = lw2 - rfz;
            sp2 = sp2 + rfz;
            float melt = fminf(pm, sp2 + snow);
            sp2 = sp2 + snow - melt;
            cm2 = (sp2 > NZF) ? (cm2 + melt) : 0.0f;
            float wrf  = fmaxf(fcsum * (1.0f - Ccum * cm2), fcmin);
            float wret = wrf * sp2;
            float wtmp = lw2 + melt + rain;
            o2 = fmaxf(wtmp - wret, 0.0f);
            lw2 = (o2 > 0.0f) ? wret : wtmp;
            cm2 = (sp2 > NZF) ? (cm2 + melt) : 0.0f;    // reference quirk: cm updated twice
        }

        // --- snobal_simple ---
        float o3;
        {
            float ddf  = fminf(ddfsum, fmaf(ddfK, cm3, ddf_min));
            float pm   = fmaxf(ddf * (tm - Tbm), 0.0f);
            float melt = fminf(pm, sp3);
            sp3 = sp3 + snow - melt;
            o3 = melt + rain;
            cm3 = (sp3 > NZF) ? (cm3 + melt) : 0.0f;
        }

        // --- vadose / phreatic chain ---
        float rr = w1 * o1 + w2 * o2 + w3 * o3;
        float vv = vad * inv_vmax;
        float sprop = fminf(fmaxf(vv, NZF), 1.0f - NZF);
        float l1 = flog2(1.0f - sprop);
        float phbv = fexp2(hbv_beta * l1);
        float pvic = fexp2(vic_beta * l1);
        float inf = w4 * rr * phbv + w5 * rr * (1.0f - hmets_alpha * vv) + w6 * rr * (1.0f - pvic);
        inf = fminf(fmaxf(inf, 0.0f), rr);
        float surface = rr - inf;
        vad += inf;
        vv = vad * inv_vmax;
        sprop = fminf(fmaxf(vv, NZF), 1.0f - NZF);
        float et = fminf(pet * ET_eff * sprop, vad);
        vad -= et;
        float spq   = fexp2(quickflow_n * flog2(sprop));
        float qf_top = fminf(qf_top_coef * spq, vad);
        float qf_vic = fminf(mmax * spq, vad);
        float qf = fminf(w7qk * vad + w8 * qf_top + w9 * qf_vic, vad);
        vad -= qf;
        float perc = cv2p * vad;
        vad -= perc;
        phr += perc;
        float pb = fexp2(baseflow_n * flog2(fmaxf(phr, NZF)));
        float bf = fminf(c_b1 * phr + c_b2 * pb, phr);
        phr -= bf;

        const float qt = surface + qf;
        const float bt = bf;

        // --- fused routing: rolling 15-wide future window ---
        #pragma unroll
        for (int k = 0; k < L_UHN; ++k)
            fut[k] = fmaf(uh1[k], qt, fmaf(uh2[k], bt, fut[k]));
        out[(size_t)t * G_CELLS + g] = fut[0];
        #pragma unroll
        for (int k = 0; k < L_UHN - 1; ++k) fut[k] = fut[k + 1];
        fut[L_UHN - 1] = 0.0f;

        cp = np_; ct = nt_; cpe = npe_;
    }
}

extern "C" void kernel_launch(void* const* d_in, const int* in_sizes, int n_in,
                              void* d_out, int out_size, void* d_ws, size_t ws_size,
                              hipStream_t stream) {
    const float* x      = (const float*)d_in[0];
    const float* params = (const float*)d_in[1];
    float* out          = (float*)d_out;
    blend_scan_kernel<<<dim3(G_CELLS / 256), dim3(256), 0, stream>>>(x, params, out);
}

// Round 4
// 163.417 us; speedup vs baseline: 1.3071x; 1.3071x over previous
//
#include <hip/hip_runtime.h>

#define T_STEPS 512
#define G_CELLS 4096
#define L_UHN   15
#define GRP     8
#define NZF     1e-5f
#define LOG2E   1.44269504088896340736f
#define LOG2_10 3.32192809488736234787f

// raw gfx950 transcendental units: v_exp_f32 computes 2^x, v_log_f32 computes log2(x)
__device__ __forceinline__ float fexp2(float x) { return __builtin_amdgcn_exp2f(x); }
__device__ __forceinline__ float flog2(float x) { return __builtin_amdgcn_logf(x); }

__device__ __forceinline__ float fpow(float a, float b) {
    // a must be > 0
    return fexp2(b * flog2(a));
}
__device__ __forceinline__ float fexp(float x) {        // e^x
    return fexp2(x * LOG2E);
}
__device__ __forceinline__ float fsigmoid(float v) {
    return 1.0f / (1.0f + fexp(-v));
}
__device__ __forceinline__ float fdescale(float s, float lo, float hi) {
    return lo + s * (hi - lo);
}

__global__ __launch_bounds__(256) void blend_scan_kernel(
    const float* __restrict__ x,       // (T, G, 3)
    const float* __restrict__ params,  // (T, G, 39)
    float* __restrict__ out)           // (T, G)
{
    const int g = blockIdx.x * blockDim.x + threadIdx.x;
    if (g >= G_CELLS) return;

    // ---- load raw params for this cell (last timestep) ----
    const float* pp = params + ((size_t)(T_STEPS - 1) * G_CELLS + (size_t)g) * 39;
    float raw[39];
    #pragma unroll
    for (int i = 0; i < 39; ++i) raw[i] = pp[i];

    // ---- unpack physical params ----
    const float ddf_min     = fdescale(fsigmoid(raw[0]),  0.0f, 20.0f);
    const float ddf_plus    = fdescale(fsigmoid(raw[1]),  0.0f, 20.0f);
    const float Kcum        = fdescale(fsigmoid(raw[2]),  0.01f, 0.2f);
    const float Kf          = fdescale(fsigmoid(raw[3]),  0.0f, 5.0f);
    const float exp_fe      = fdescale(fsigmoid(raw[4]),  0.0f, 1.0f);
    const float Tbf         = fdescale(fsigmoid(raw[5]), -5.0f, 2.0f);
    const float Ccum        = fdescale(fsigmoid(raw[6]),  0.005f, 0.05f);
    const float SWI         = fdescale(fsigmoid(raw[7]),  0.0f, 0.4f);
    const float Tbm         = fdescale(fsigmoid(raw[8]), -2.0f, 3.0f);
    const float fcmin       = fdescale(fsigmoid(raw[9]),  0.0f, 0.1f);
    const float fcmin_plus  = fdescale(fsigmoid(raw[10]), 0.01f, 0.25f);
    const float vmax        = fdescale(fsigmoid(raw[11]), 0.001f, 500.0f);
    const float hmets_alpha = fdescale(fsigmoid(raw[12]), 0.0f, 1.0f);
    const float vic_beta    = fdescale(fsigmoid(raw[13]), 0.1f, 3.0f);
    const float hbv_beta    = fdescale(fsigmoid(raw[14]), 0.5f, 3.0f);
    const float quickflow_k = fdescale(fsigmoid(raw[15]), -5.0f, -2.0f);
    const float quickflow_n = fdescale(fsigmoid(raw[16]), 0.5f, 2.0f);
    const float mmax        = fdescale(fsigmoid(raw[17]), 0.0f, 100.0f);
    const float lamb        = fdescale(fsigmoid(raw[18]), 5.0f, 10.0f);
    const float baseflow_k  = fdescale(fsigmoid(raw[19]), -5.0f, -1.0f);
    const float baseflow_n  = fdescale(fsigmoid(raw[20]), 0.5f, 2.0f);
    const float ET_eff      = fdescale(fsigmoid(raw[21]), 0.0f, 3.0f);
    const float cv2p        = fdescale(fsigmoid(raw[22]), 1e-5f, 0.02f);
    // raw[23] (coef_phreatic) unused by forward

    // ---- softmax weight groups (on raw values, like reference) ----
    float w1, w2, w3, w4, w5, w6, w7, w8, w9, w10, w11;
    {
        float m = fmaxf(fmaxf(raw[24], raw[25]), raw[26]);
        float e0 = fexp(raw[24] - m), e1 = fexp(raw[25] - m), e2 = fexp(raw[26] - m);
        float inv = 1.0f / (e0 + e1 + e2);
        w1 = e0 * inv; w2 = e1 * inv; w3 = e2 * inv;
    }
    {
        float m = fmaxf(fmaxf(raw[27], raw[28]), raw[29]);
        float e0 = fexp(raw[27] - m), e1 = fexp(raw[28] - m), e2 = fexp(raw[29] - m);
        float inv = 1.0f / (e0 + e1 + e2);
        w4 = e0 * inv; w5 = e1 * inv; w6 = e2 * inv;
    }
    {
        float m = fmaxf(fmaxf(raw[30], raw[31]), raw[32]);
        float e0 = fexp(raw[30] - m), e1 = fexp(raw[31] - m), e2 = fexp(raw[32] - m);
        float inv = 1.0f / (e0 + e1 + e2);
        w7 = e0 * inv; w8 = e1 * inv; w9 = e2 * inv;
    }
    {
        float m = fmaxf(raw[33], raw[34]);
        float e0 = fexp(raw[33] - m), e1 = fexp(raw[34] - m);
        float inv = 1.0f / (e0 + e1);
        w10 = e0 * inv; w11 = e1 * inv;
    }

    // ---- routing params + gamma unit hydrographs ----
    const float a1 = fdescale(fsigmoid(raw[35]), 0.3f, 20.0f);
    const float b1 = fdescale(fsigmoid(raw[36]), 0.01f, 5.0f);
    const float a2 = fdescale(fsigmoid(raw[37]), 0.5f, 13.0f);
    const float b2 = fdescale(fsigmoid(raw[38]), 0.15f, 1.5f);

    const float LOG2T[L_UHN] = {
        -1.0f, 0.58496250072116f, 1.32192809488736f, 1.80735492205760f,
        2.16992500144231f, 2.45943161863730f, 2.70043971814109f,
        2.90689059560852f, 3.08746284125034f, 3.24792751344359f,
        3.39231742277876f, 3.52356195605701f, 3.64385618977472f,
        3.75488750216347f, 3.85798099512757f };

    float uh1[L_UHN], uh2[L_UHN];
    {
        float rb1 = LOG2E / b1, rb2 = LOG2E / b2;
        float s1 = 0.0f, s2 = 0.0f;
        #pragma unroll
        for (int k = 0; k < L_UHN; ++k) {
            float tk = (float)k + 0.5f;
            float v1 = fexp2((a1 - 1.0f) * LOG2T[k] - tk * rb1);
            float v2 = fexp2((a2 - 1.0f) * LOG2T[k] - tk * rb2);
            uh1[k] = v1; uh2[k] = v2; s1 += v1; s2 += v2;
        }
        float i1 = 1.0f / s1, i2 = 1.0f / s2;
        #pragma unroll
        for (int k = 0; k < L_UHN; ++k) { uh1[k] *= i1; uh2[k] *= i2; }
    }

    // ---- per-cell loop constants ----
    const float ddfsum      = ddf_min + ddf_plus;
    const float ddfK        = ddf_min * Kcum;
    const float inv_vmax    = 1.0f / vmax;
    const float qk10        = fexp2(quickflow_k * LOG2_10);
    const float bk10        = fexp2(baseflow_k * LOG2_10);
    const float qf_top_coef = mmax * (vmax / quickflow_n) * fexp2(-quickflow_n * flog2(lamb));
    const float fcsum       = fcmin + fcmin_plus;
    const float c_b1        = w10 * bk10;
    const float c_b2        = w11 * bk10;
    const float w7qk        = w7 * qk10;

    // ---- state ----
    float sp1 = 0.f, lw1 = 0.f, cm1 = 0.f;
    float sp2 = 0.f, lw2 = 0.f, cm2 = 0.f;
    float sp3 = 0.f, cm3 = 0.f;
    float vad = 0.f, phr = 0.f;

    float fut[L_UHN];
    #pragma unroll
    for (int k = 0; k < L_UHN; ++k) fut[k] = 0.0f;

    // ---- double-buffered forcing prefetch: GRP steps per group ----
    float cx[GRP][3], nx[GRP][3];
    #pragma unroll
    for (int j = 0; j < GRP; ++j) {
        size_t a = ((size_t)j * G_CELLS + (size_t)g) * 3;
        cx[j][0] = x[a]; cx[j][1] = x[a + 1]; cx[j][2] = x[a + 2];
    }

    for (int tb = 0; tb < T_STEPS / GRP; ++tb) {
        // issue next group's loads (independent; latency hidden under compute below)
        const int base_next = (tb + 1) * GRP;
        #pragma unroll
        for (int j = 0; j < GRP; ++j) {
            int tt = base_next + j;
            if (tt >= T_STEPS) tt = T_STEPS - 1;   // harmless clamp for the final group
            size_t a = ((size_t)tt * G_CELLS + (size_t)g) * 3;
            nx[j][0] = x[a]; nx[j][1] = x[a + 1]; nx[j][2] = x[a + 2];
        }

        #pragma unroll
        for (int j = 0; j < GRP; ++j) {
            const int t = tb * GRP + j;
            const float prcp = cx[j][0], tm = cx[j][1], pet = cx[j][2];
            const float rain = (tm > 0.0f) ? prcp : 0.0f;
            const float snow = prcp - rain;
            const float frz_pot = fmaxf(Tbf - tm, NZF);

            // --- snobal_hbv ---
            float o1;
            {
                float ddf  = fminf(ddfsum, fmaf(ddfK, cm1, ddf_min));
                float pm   = fmaxf(ddf * (tm - Tbm), 0.0f);
                float rfz  = fminf(Kf * frz_pot, lw1);
                sp1 = sp1 + snow + rfz;
                float melt = fminf(pm, sp1 + snow + rfz);   // reference quirk: sp already updated
                cm1 = (sp1 > NZF) ? (cm1 + melt) : 0.0f;
                sp1 = fmaxf(sp1 - melt, NZF);
                float wret = SWI * sp1;
                float wtmp = lw1 + melt + rain;
                o1 = fmaxf(wtmp - wret, 0.0f);
                lw1 = (o1 > 0.0f) ? wret : wtmp;
            }

            // --- snobal_hmets ---
            float o2;
            {
                float ddf  = fminf(ddfsum, fmaf(ddfK, cm2, ddf_min));
                float pm   = fmaxf(ddf * (tm - Tbm), 0.0f);
                float pfz  = Kf * fpow(frz_pot, exp_fe);
                float rfz  = fminf(pfz, lw2);
                lw2 = lw2 - rfz;
                sp2 = sp2 + rfz;
                float melt = fminf(pm, sp2 + snow);
                sp2 = sp2 + snow - melt;
                cm2 = (sp2 > NZF) ? (cm2 + melt) : 0.0f;
                float wrf  = fmaxf(fcsum * (1.0f - Ccum * cm2), fcmin);
                float wret = wrf * sp2;
                float wtmp = lw2 + melt + rain;
                o2 = fmaxf(wtmp - wret, 0.0f);
                lw2 = (o2 > 0.0f) ? wret : wtmp;
                cm2 = (sp2 > NZF) ? (cm2 + melt) : 0.0f;    // reference quirk: cm updated twice
            }

            // --- snobal_simple ---
            float o3;
            {
                float ddf  = fminf(ddfsum, fmaf(ddfK, cm3, ddf_min));
                float pm   = fmaxf(ddf * (tm - Tbm), 0.0f);
                float melt = fminf(pm, sp3);
                sp3 = sp3 + snow - melt;
                o3 = melt + rain;
                cm3 = (sp3 > NZF) ? (cm3 + melt) : 0.0f;
            }

            // --- vadose / phreatic chain ---
            float rr = w1 * o1 + w2 * o2 + w3 * o3;
            float vv = vad * inv_vmax;
            float sprop = fminf(fmaxf(vv, NZF), 1.0f - NZF);
            float l1 = flog2(1.0f - sprop);
            float phbv = fexp2(hbv_beta * l1);
            float pvic = fexp2(vic_beta * l1);
            float inf = w4 * rr * phbv + w5 * rr * (1.0f - hmets_alpha * vv) + w6 * rr * (1.0f - pvic);
            inf = fminf(fmaxf(inf, 0.0f), rr);
            float surface = rr - inf;
            vad += inf;
            vv = vad * inv_vmax;
            sprop = fminf(fmaxf(vv, NZF), 1.0f - NZF);
            float et = fminf(pet * ET_eff * sprop, vad);
            vad -= et;
            float spq   = fexp2(quickflow_n * flog2(sprop));
            float qf_top = fminf(qf_top_coef * spq, vad);
            float qf_vic = fminf(mmax * spq, vad);
            float qf = fminf(w7qk * vad + w8 * qf_top + w9 * qf_vic, vad);
            vad -= qf;
            float perc = cv2p * vad;
            vad -= perc;
            phr += perc;
            float pb = fexp2(baseflow_n * flog2(fmaxf(phr, NZF)));
            float bf = fminf(c_b1 * phr + c_b2 * pb, phr);
            phr -= bf;

            const float qt = surface + qf;
            const float bt = bf;

            // --- fused routing: rolling 15-wide future window ---
            #pragma unroll
            for (int k = 0; k < L_UHN; ++k)
                fut[k] = fmaf(uh1[k], qt, fmaf(uh2[k], bt, fut[k]));
            out[(size_t)t * G_CELLS + g] = fut[0];
            #pragma unroll
            for (int k = 0; k < L_UHN - 1; ++k) fut[k] = fut[k + 1];
            fut[L_UHN - 1] = 0.0f;
        }

        // rotate buffers (register moves; mostly renamed away by the compiler)
        #pragma unroll
        for (int j = 0; j < GRP; ++j) {
            cx[j][0] = nx[j][0]; cx[j][1] = nx[j][1]; cx[j][2] = nx[j][2];
        }
    }
}

extern "C" void kernel_launch(void* const* d_in, const int* in_sizes, int n_in,
                              void* d_out, int out_size, void* d_ws, size_t ws_size,
                              hipStream_t stream) {
    const float* x      = (const float*)d_in[0];
    const float* params = (const float*)d_in[1];
    float* out          = (float*)d_out;
    blend_scan_kernel<<<dim3(G_CELLS / 256), dim3(256), 0, stream>>>(x, params, out);
}